// Round 12
// baseline (1131.379 us; speedup 1.0000x reference)
//
#include <hip/hip_runtime.h>
#include <hip/hip_bf16.h>
#include <math.h>

// ---------------- problem constants ----------------
#define D        256
#define NINNER   2048
#define NROW     2049          // 2048 + dustbin
#define SP       2064          // padded row stride (floats), 16B-aligned rows
#define ITERS_N  100
#define EPS_F    0.8f
#define TAU_F    1.02f
#define NB       128           // persistent blocks (fewer, fatter agents)
#define NT       512           // threads per block
#define RPB      16            // rows/cols owned per block

typedef unsigned long long u64;

// exchange: u64 slots = (tag<<32)|float_bits, double-buffered by tag parity
#define PSTRIDE  2112u         // u64 slots per buffer (2048 + dustbin + pad)

// ws layout (in floats)
#define SZ_MAT   (2049u * 2064u)          // 4229136
#define OFF_E    0u
#define OFF_F    SZ_MAT
#define OFF_WUP  (2u * SZ_MAT)                  // u64[2][PSTRIDE]
#define OFF_WVP  (OFF_WUP + 4u * PSTRIDE)
#define OFF_MAX0 (OFF_WVP + 4u * PSTRIDE)
#define OFF_IDX0 (OFF_MAX0 + 2048u)
#define OFF_IDX1 (OFF_IDX0 + 2048u)
#define OFF_MS0  (OFF_IDX1 + 2048u)
#define OFF_VLD0 (OFF_MS0 + 2048u)

// d_out layout (floats)
#define OOFF_Z   0u
#define OOFF_I0  (2049u * 2049u)          // 4198401
#define OOFF_I1  (OOFF_I0 + 2048u)
#define OOFF_S0  (OOFF_I1 + 2048u)
#define OOFF_S1  (OOFF_S0 + 2048u)

__device__ __forceinline__ float    pair_val(u64 x) { return __uint_as_float((unsigned)x); }
__device__ __forceinline__ unsigned pair_tag(u64 x) { return (unsigned)(x >> 32); }
__device__ __forceinline__ u64 make_pair(float v, unsigned t) {
    return ((u64)t << 32) | (u64)__float_as_uint(v);
}

// ---------------- K1: fp32 GEMM -> E = exp(scores), F = E^T (fused) ----------------
__global__ __launch_bounds__(256) void k_gemm(const float* __restrict__ A,
                                              const float* __restrict__ Bm,
                                              float* __restrict__ E,
                                              float* __restrict__ F) {
    __shared__ float As[8][64];
    __shared__ float Bs[8][64];
    const int tid = threadIdx.x;
    const int tx = tid & 15, ty = tid >> 4;
    const int row0 = blockIdx.y * 64, col0 = blockIdx.x * 64;
    float acc[4][4] = {};
    const int lr = tid >> 6, lc = tid & 63;
    for (int k0 = 0; k0 < D; k0 += 8) {
        As[lr][lc]     = A[(k0 + lr) * NINNER + row0 + lc];
        As[lr + 4][lc] = A[(k0 + lr + 4) * NINNER + row0 + lc];
        Bs[lr][lc]     = Bm[(k0 + lr) * NINNER + col0 + lc];
        Bs[lr + 4][lc] = Bm[(k0 + lr + 4) * NINNER + col0 + lc];
        __syncthreads();
#pragma unroll
        for (int kk = 0; kk < 8; ++kk) {
            const float4 av = *(const float4*)&As[kk][ty * 4];
            const float4 bv = *(const float4*)&Bs[kk][tx * 4];
            const float a_[4] = {av.x, av.y, av.z, av.w};
            const float b_[4] = {bv.x, bv.y, bv.z, bv.w};
#pragma unroll
            for (int r = 0; r < 4; ++r)
#pragma unroll
                for (int c = 0; c < 4; ++c)
                    acc[r][c] = fmaf(a_[r], b_[c], acc[r][c]);
        }
        __syncthreads();
    }
    float o[4][4];
#pragma unroll
    for (int r = 0; r < 4; ++r)
#pragma unroll
        for (int c = 0; c < 4; ++c)
            o[r][c] = expf(acc[r][c] * 0.0625f);
    const int row = row0 + ty * 4, col = col0 + tx * 4;
#pragma unroll
    for (int r = 0; r < 4; ++r)     // E tile
        *(float4*)(E + (size_t)(row + r) * SP + col)
            = make_float4(o[r][0], o[r][1], o[r][2], o[r][3]);
#pragma unroll
    for (int c = 0; c < 4; ++c)     // F tile (transposed)
        *(float4*)(F + (size_t)(col + c) * SP + row)
            = make_float4(o[0][c], o[1][c], o[2][c], o[3][c]);
}

// ---------------- K2: bins + wv pair init (tag 0) ----------------
__global__ __launch_bounds__(256) void k_init(float* __restrict__ E,
                                              float* __restrict__ F,
                                              u64* __restrict__ wvb0,
                                              const float* __restrict__ alpha) {
    const int t = blockIdx.x * 256 + threadIdx.x;
    const float ea = expf(alpha[0]);
    if (t < NINNER) {
        E[(size_t)t * SP + NINNER] = ea;        // E bin column (epilogue only)
        F[(size_t)t * SP + NINNER] = ea;        // F bin column
        wvb0[t] = make_pair(1.0f, 0u);          // v0 = 0 -> wv = 1, tag 0
    }
    if (t <= NINNER) {
        E[(size_t)NINNER * SP + t] = ea;        // E bin row (+corner)
        F[(size_t)NINNER * SP + t] = ea;        // F bin row (+corner)
    }
}

// ---------------- masked hot poll (4 slots/thread) + light backoff ----------------
__device__ __forceinline__ void poll4(const u64* buf, int tid, unsigned want, float* w) {
    u64 a[4];
#pragma unroll
    for (int q = 0; q < 4; ++q)
        a[q] = __hip_atomic_load(buf + q * 512 + tid, __ATOMIC_RELAXED, __HIP_MEMORY_SCOPE_AGENT);
    for (;;) {
        unsigned miss = 0u;
#pragma unroll
        for (int q = 0; q < 4; ++q)
            miss |= (pair_tag(a[q]) != want) ? (1u << q) : 0u;
        if (!miss) break;
        __builtin_amdgcn_s_sleep(2);     // ~128 cyc backoff
#pragma unroll
        for (int q = 0; q < 4; ++q)
            if (miss & (1u << q))
                a[q] = __hip_atomic_load(buf + q * 512 + tid, __ATOMIC_RELAXED, __HIP_MEMORY_SCOPE_AGENT);
    }
#pragma unroll
    for (int q = 0; q < 4; ++q) w[q] = pair_val(a[q]);
}

// ---------------- K3: persistent Sinkhorn — 128 fat agents ----------------
// Block b owns rows [16b,16b+16) of E and cols [16b,16b+16) of F in registers
// (eR/fR[r][q] = matrix[16b+r][q*512+tid]). wu/wv exchanged as (tag,value)
// u64 atoms, parity double-buffered (causal skew < 2 iters per parity buffer;
// 0xAA poison never matches a wanted tag 0..100). Dustbin potentials locally
// replicated (r6). Fewer agents -> shorter straggler tail per phase.
__global__ __launch_bounds__(512, 2) void k_sinkhorn(const float* __restrict__ E,
                                                     const float* __restrict__ F,
                                                     u64* wub, u64* wvb,
                                                     const float* __restrict__ alpha) {
    const int b = blockIdx.x, tid = threadIdx.x;
    const int lane = tid & 63, wid = tid >> 6;     // wid < 8
    const int base = b * RPB;
    const bool lastb = (b == NB - 1);
    __shared__ float red[2][8][RPB + 1];

    const float norm = -8.317766166719343f;            // -log(4096)
    const float logbin = 7.624618986159398f + norm;     // log(2048) + norm
    const float ea = expf(alpha[0]);

    // register-resident fragments: eR[r][q] = E[base+r][q*512+tid]
    float eR[RPB][4], fR[RPB][4];
#pragma unroll
    for (int r = 0; r < RPB; ++r) {
        const float* rowE = E + (size_t)(base + r) * SP;
        const float* rowF = F + (size_t)(base + r) * SP;
#pragma unroll
        for (int q = 0; q < 4; ++q) {
            eR[r][q] = rowE[q * 512 + tid];
            fR[r][q] = rowF[q * 512 + tid];
        }
    }

    float u = 0.0f, v = 0.0f;              // potentials for row/col base+tid (tid<16)
    float ub = 0.0f, vb = 0.0f;            // dustbin potentials — local replicas
    float eub = 1.0f, evb = 1.0f;

    for (int it = 0; it < ITERS_N; ++it) {
        // ---- phase A: consume wv tag it, produce wu tag it+1 ----
        {
            const u64* src = wvb + (size_t)(it & 1) * PSTRIDE;
            u64* dst = wub + (size_t)((it + 1) & 1) * PSTRIDE;
            const unsigned prod = (unsigned)(it + 1);
            float w[4];
            poll4(src, tid, (unsigned)it, w);
            float p[RPB];
#pragma unroll
            for (int r = 0; r < RPB; ++r) {
                float s = 0.0f;
#pragma unroll
                for (int q = 0; q < 4; ++q) s = fmaf(eR[r][q], w[q], s);
                p[r] = s;
            }
            float t = w[0] + w[1] + w[2] + w[3];
#pragma unroll
            for (int r = 0; r < RPB; ++r) {
                float s = p[r];
#pragma unroll
                for (int m = 1; m < 64; m <<= 1) s += __shfl_xor(s, m, 64);
                if (lane == 0) red[0][wid][r] = s;
            }
#pragma unroll
            for (int m = 1; m < 64; m <<= 1) t += __shfl_xor(t, m, 64);
            if (lane == 0) red[0][wid][RPB] = t;
            __syncthreads();
            if (tid < RPB) {
                float S = ea * evb;
#pragma unroll
                for (int k = 0; k < 8; ++k) S += red[0][k][tid];
                const float unew = (norm - logf(S)) / TAU_F;
                u = u + EPS_F * (unew - u);
                __hip_atomic_store(dst + base + tid, make_pair(expf(u), prod),
                                   __ATOMIC_RELAXED, __HIP_MEMORY_SCOPE_AGENT);
            }
            // local dustbin update (all threads, identical result)
            float tsum = 0.0f;
#pragma unroll
            for (int k = 0; k < 8; ++k) tsum += red[0][k][RPB];
            const float Sbin = ea * (tsum + evb);
            ub = ub + EPS_F * ((logbin - logf(Sbin)) / TAU_F - ub);
            eub = expf(ub);
        }
        // ---- phase B: consume wu tag it+1, produce wv tag it+1 ----
        {
            const u64* src = wub + (size_t)((it + 1) & 1) * PSTRIDE;
            u64* dst = wvb + (size_t)((it + 1) & 1) * PSTRIDE;
            const unsigned prod = (unsigned)(it + 1);
            float w[4];
            poll4(src, tid, prod, w);
            float p[RPB];
#pragma unroll
            for (int r = 0; r < RPB; ++r) {
                float s = 0.0f;
#pragma unroll
                for (int q = 0; q < 4; ++q) s = fmaf(fR[r][q], w[q], s);
                p[r] = s;
            }
            float t = w[0] + w[1] + w[2] + w[3];
#pragma unroll
            for (int r = 0; r < RPB; ++r) {
                float s = p[r];
#pragma unroll
                for (int m = 1; m < 64; m <<= 1) s += __shfl_xor(s, m, 64);
                if (lane == 0) red[1][wid][r] = s;
            }
#pragma unroll
            for (int m = 1; m < 64; m <<= 1) t += __shfl_xor(t, m, 64);
            if (lane == 0) red[1][wid][RPB] = t;
            __syncthreads();
            if (tid < RPB) {
                float T = ea * eub;
#pragma unroll
                for (int k = 0; k < 8; ++k) T += red[1][k][tid];
                const float vnew = (norm - logf(T)) / TAU_F;
                v = v + EPS_F * (vnew - v);
                __hip_atomic_store(dst + base + tid, make_pair(expf(v), prod),
                                   __ATOMIC_RELAXED, __HIP_MEMORY_SCOPE_AGENT);
            }
            float tsum = 0.0f;
#pragma unroll
            for (int k = 0; k < 8; ++k) tsum += red[1][k][RPB];
            const float Tbin = ea * (tsum + eub);
            vb = vb + EPS_F * ((logbin - logf(Tbin)) / TAU_F - vb);
            evb = expf(vb);
        }
    }
    // publish final dustbin scalings (tag 100 -> parity 0) for the epilogue
    if (lastb && tid == 0) {
        __hip_atomic_store(wub + NINNER, make_pair(eub, (unsigned)ITERS_N),
                           __ATOMIC_RELAXED, __HIP_MEMORY_SCOPE_AGENT);
        __hip_atomic_store(wvb + NINNER, make_pair(evb, (unsigned)ITERS_N),
                           __ATOMIC_RELAXED, __HIP_MEMORY_SCOPE_AGENT);
    }
}

// ---------------- K4: fused epilogue — out0 = exp(Z), row argmax, col argmax ----------
// final wu/wv: tag 100 (even) -> parity-0 buffer halves -> .x of float2 pairs
__global__ __launch_bounds__(256) void k_finish(const float* __restrict__ E,
                                                const float* __restrict__ F,
                                                const float2* __restrict__ wup,
                                                const float2* __restrict__ wvp,
                                                float* __restrict__ out,
                                                float* __restrict__ max0,
                                                int* __restrict__ idx0,
                                                int* __restrict__ idx1) {
    const int i = blockIdx.x;                 // 0..2048
    const int tid = threadIdx.x;
    const int lane = tid & 63, wid = tid >> 6;
    __shared__ float sb[4]; __shared__ int si[4];

    // --- row part: write out row i, argmax over inner cols ---
    {
        const float wui = wup[i].x * 4096.0f;     // * exp(-norm)
        const float* row = E + (size_t)i * SP;
        float best = -1.0f; int bidx = 0;
        for (int j = tid; j < NROW; j += 256) {
            const float val = row[j] * wvp[j].x * wui;
            out[(size_t)i * NROW + j] = val;
            if (j < NINNER && val > best) { best = val; bidx = j; }
        }
        if (i < NINNER) {
#pragma unroll
            for (int m = 1; m < 64; m <<= 1) {
                const float ob = __shfl_xor(best, m, 64);
                const int   oi = __shfl_xor(bidx, m, 64);
                if (ob > best || (ob == best && oi < bidx)) { best = ob; bidx = oi; }
            }
            if (lane == 0) { sb[wid] = best; si[wid] = bidx; }
            __syncthreads();
            if (tid == 0) {
                for (int k = 1; k < 4; ++k)
                    if (sb[k] > best || (sb[k] == best && si[k] < bidx)) { best = sb[k]; bidx = si[k]; }
                max0[i] = best; idx0[i] = bidx;
            }
        }
    }

    // --- col part: argmax of column i over inner rows (via F) ---
    if (i < NINNER) {
        __syncthreads();                          // sb/si reuse safety
        const float* row = F + (size_t)i * SP;
        float best = -1.0f; int bidx = 0;
        for (int r = tid; r < NINNER; r += 256) {
            const float q = row[r] * wup[r].x;
            if (q > best) { best = q; bidx = r; }
        }
#pragma unroll
        for (int m = 1; m < 64; m <<= 1) {
            const float ob = __shfl_xor(best, m, 64);
            const int   oi = __shfl_xor(bidx, m, 64);
            if (ob > best || (ob == best && oi < bidx)) { best = ob; bidx = oi; }
        }
        if (lane == 0) { sb[wid] = best; si[wid] = bidx; }
        __syncthreads();
        if (tid == 0) {
            for (int k = 1; k < 4; ++k)
                if (sb[k] > best || (sb[k] == best && si[k] < bidx)) { best = sb[k]; bidx = si[k]; }
            idx1[i] = bidx;
        }
    }
}

// ---------------- K5a/K5b: mutual matching ----------------
__global__ __launch_bounds__(256) void k_match0(const float* __restrict__ max0,
                                                const int* __restrict__ idx0,
                                                const int* __restrict__ idx1,
                                                float* __restrict__ ms0,
                                                int* __restrict__ vld0,
                                                float* __restrict__ out) {
    const int i = blockIdx.x * 256 + threadIdx.x;
    if (i >= NINNER) return;
    const int j = idx0[i];
    const bool mut = (idx1[j] == i);
    const float ms = mut ? max0[i] : 0.0f;
    const bool val = mut && (ms > 0.2f);
    ms0[i] = ms; vld0[i] = val ? 1 : 0;
    out[OOFF_I0 + i] = val ? (float)j : -1.0f;
    out[OOFF_S0 + i] = ms;
}
__global__ __launch_bounds__(256) void k_match1(const int* __restrict__ idx0,
                                                const int* __restrict__ idx1,
                                                const float* __restrict__ ms0,
                                                const int* __restrict__ vld0,
                                                float* __restrict__ out) {
    const int j = blockIdx.x * 256 + threadIdx.x;
    if (j >= NINNER) return;
    const int i = idx1[j];
    const bool mut = (idx0[i] == j);
    const float ms = mut ? ms0[i] : 0.0f;
    const bool val = mut && (vld0[i] != 0);
    out[OOFF_I1 + j] = val ? (float)i : -1.0f;
    out[OOFF_S1 + j] = ms;
}

// ---------------- host ----------------
extern "C" void kernel_launch(void* const* d_in, const int* in_sizes, int n_in,
                              void* d_out, int out_size, void* d_ws, size_t ws_size,
                              hipStream_t stream) {
    const float* A     = (const float*)d_in[0];   // mdesc0 (1,256,2048)
    const float* Bm    = (const float*)d_in[1];   // mdesc1 (1,256,2048)
    const float* alpha = (const float*)d_in[2];   // bin_score scalar

    float* ws = (float*)d_ws;
    float* E    = ws + OFF_E;
    float* F    = ws + OFF_F;
    u64*   wub  = (u64*)(ws + OFF_WUP);
    u64*   wvb  = (u64*)(ws + OFF_WVP);
    float* max0 = ws + OFF_MAX0;
    int*   idx0 = (int*)(ws + OFF_IDX0);
    int*   idx1 = (int*)(ws + OFF_IDX1);
    float* ms0  = ws + OFF_MS0;
    int*   vld0 = (int*)(ws + OFF_VLD0);
    float* out  = (float*)d_out;

    k_gemm<<<dim3(32, 32), 256, 0, stream>>>(A, Bm, E, F);
    k_init<<<dim3(9), 256, 0, stream>>>(E, F, wvb, alpha);
    k_sinkhorn<<<dim3(NB), NT, 0, stream>>>(E, F, wub, wvb, alpha);
    // final tag 100 (even) -> parity-0 halves of both pair buffers
    k_finish<<<dim3(NROW), 256, 0, stream>>>(E, F, (const float2*)wub, (const float2*)wvb,
                                             out, max0, idx0, idx1);
    k_match0<<<dim3(8), 256, 0, stream>>>(max0, idx0, idx1, ms0, vld0, out);
    k_match1<<<dim3(8), 256, 0, stream>>>(idx0, idx1, ms0, vld0, out);
}